// Round 26
// baseline (219.299 us; speedup 1.0000x reference)
//
#include <hip/hip_runtime.h>
#include <stdint.h>

typedef __attribute__((ext_vector_type(8))) short short8;
typedef __attribute__((ext_vector_type(4))) float f32x4;

constexpr int      BATCH    = 524288;
constexpr int      ARRAY_SZ = 262144;
constexpr uint64_t PRIME    = 2038074743ull;
constexpr uint32_t RANGE    = 262137u;          // ARRAY_SZ - 8 + 1
constexpr int      NMT      = BATCH / 16;       // 32768 M-tiles of 16 elements
// Sign-certainty bound, 2-split (hi+mid) MFMA vs sequential-fmaf reference
// (derivation r17, verified absmax 0.0 r17-r25): total error < 5.4e-5 *
// Sum|x|, margin EPS = 8e-5. Flagged entries recomputed with the sequential
// fmaf chain proven bit-exact in rounds 1-25.
constexpr float    EPS      = 8e-5f;

__device__ __forceinline__ void load_hash_consts(const void* rnd_raw,
                                                 uint64_t& HA, uint64_t& HB, uint64_t& HC0)
{
    const uint64_t first8 = *reinterpret_cast<const uint64_t*>(rnd_raw);
    if (first8 == PRIME) {
        const long long* r64 = reinterpret_cast<const long long*>(rnd_raw);
        HA = (uint64_t)r64[1]; HB = (uint64_t)r64[2]; HC0 = (uint64_t)r64[3];
    } else {
        const int* r32 = reinterpret_cast<const int*>(rnd_raw);
        HA  = (uint64_t)(uint32_t)r32[1];
        HB  = (uint64_t)(uint32_t)r32[2];
        HC0 = (uint64_t)(uint32_t)r32[3];
    }
}

// ===== Kernel 0: precompute loc + w tables for all (chunk, srp) combos =====
__global__ __launch_bounds__(256, 1)
void lma_tab(const float* __restrict__ hw,
             const void* __restrict__ rnd_raw,
             uint32_t* __restrict__ locTab,   // [4096]
             float* __restrict__ wTab)        // [4096][8]
{
    uint64_t HA, HB, HC0;
    load_hash_consts(rnd_raw, HA, HB, HC0);

    const int t   = blockIdx.x * 256 + threadIdx.x;   // 0..4095
    const int srp = t & 255;
    const int cc  = t >> 8;                           // 0..15
    const int cch = cc & 7;

    const uint64_t hh  = (HA * (uint64_t)srp + HB * (uint64_t)cch + HC0) % PRIME;
    const uint32_t loc = (uint32_t)hh % RANGE + ((cc >> 3) ? (uint32_t)ARRAY_SZ : 0u);
    locTab[t] = loc;
#pragma unroll
    for (int j = 0; j < 8; ++j) wTab[t * 8 + j] = hw[loc + j];
}

// ===== Main kernel: MFMA + ballot + table lookups + direct stores =====
// (256,4): cap unified regs at 128/thread for 4 waves/SIMD. Live set of this
// ballot+table structure ~100-110 unified (68 arch VGPR at cap 256, r18/r19)
// -> expected no spill. Sentinel: WRITE_SIZE must stay ~403e3 KB.
__global__ __launch_bounds__(256, 4)
void lma_fusedT(const float* __restrict__ x,
                const float* __restrict__ lsh,
                const uint32_t* __restrict__ locTab,
                const float* __restrict__ wTab,
                float* __restrict__ out_idx,   // B*128 floats (idx as f32)
                float* __restrict__ out_val)   // B*64 floats
{
    __shared__ unsigned short T[128 * 128];   // lsh^T bf16, XOR-swizzled

    const int tid  = threadIdx.x;
    const int lane = tid & 63;
    const int wid  = __builtin_amdgcn_readfirstlane(tid >> 6);

    for (int it = 0; it < 16; ++it) {
        const int flat4 = it * 256 + tid;
        const int i  = flat4 >> 5;
        const int n4 = (flat4 & 31) << 2;
        const f32x4 v = *reinterpret_cast<const f32x4*>(lsh + i * 128 + n4);
#pragma unroll
        for (int d = 0; d < 4; ++d) {
            const int n = n4 + d;
            T[n * 128 + (((i >> 3) ^ (n & 15)) << 3) + (i & 7)] =
                (unsigned short)(__float_as_uint(v[d]) >> 16);
        }
    }
    __syncthreads();

    const int r    = lane & 15;
    const int g    = lane >> 4;
    const int e    = lane >> 2;
    const int c4   = lane & 3;
    const int hf   = c4 & 1;
    const int npar = c4 >> 1;
    const int shb  = 16 * (e >> 2) + 8 * hf;
    const int sel  = e & 3;
    const bool s0 = (sel == 0), s1 = (sel == 1), s2 = (sel == 2);

    const int mt0 = blockIdx.x * 4 + wid;            // grid 2048 -> stride 8192
    f32x4 xp0, xp1, xp2, xp3, xp4, xp5, xp6, xp7;
    {
        const float* xn = x + (size_t)mt0 * 16 * 128 + r * 128 + g * 8;
        xp0 = *reinterpret_cast<const f32x4*>(xn);
        xp1 = *reinterpret_cast<const f32x4*>(xn + 4);
        xp2 = *reinterpret_cast<const f32x4*>(xn + 32);
        xp3 = *reinterpret_cast<const f32x4*>(xn + 36);
        xp4 = *reinterpret_cast<const f32x4*>(xn + 64);
        xp5 = *reinterpret_cast<const f32x4*>(xn + 68);
        xp6 = *reinterpret_cast<const f32x4*>(xn + 96);
        xp7 = *reinterpret_cast<const f32x4*>(xn + 100);
    }

#pragma unroll 1
    for (int mt = mt0; mt < NMT; mt += 8192) {
        const int Mb = mt * 16;

        f32x4 acc[8];
#pragma unroll
        for (int n8 = 0; n8 < 8; ++n8) acc[n8] = (f32x4)(0.0f);
        float asum = 0.0f;

#pragma unroll
        for (int ks = 0; ks < 4; ++ks) {
            const f32x4 xa = (ks == 0) ? xp0 : (ks == 1) ? xp2 : (ks == 2) ? xp4 : xp6;
            const f32x4 xc = (ks == 0) ? xp1 : (ks == 1) ? xp3 : (ks == 2) ? xp5 : xp7;
            float xs[8] = {xa[0], xa[1], xa[2], xa[3], xc[0], xc[1], xc[2], xc[3]};
#pragma unroll
            for (int j = 0; j < 8; ++j) asum += fabsf(xs[j]);

            union { uint32_t u[4]; short8 v; } Ahi, Ami;
#pragma unroll
            for (int p = 0; p < 4; ++p) {
                const uint32_t b0 = __float_as_uint(xs[2 * p]);
                const uint32_t b1 = __float_as_uint(xs[2 * p + 1]);
                const uint32_t h0 = b0 & 0xFFFF0000u, h1 = b1 & 0xFFFF0000u;
                const float    t0 = xs[2 * p] - __uint_as_float(h0);
                const float    t1 = xs[2 * p + 1] - __uint_as_float(h1);
                const uint32_t m0 = __float_as_uint(t0) & 0xFFFF0000u;
                const uint32_t m1 = __float_as_uint(t1) & 0xFFFF0000u;
                Ahi.u[p] = h1 | (h0 >> 16);
                Ami.u[p] = m1 | (m0 >> 16);
            }
#pragma unroll
            for (int n8 = 0; n8 < 8; ++n8) {
                const short8 bf = *reinterpret_cast<const short8*>(
                    &T[(n8 * 16 + r) * 128 + (((ks * 4 + g) ^ r) << 3)]);
                acc[n8] = __builtin_amdgcn_mfma_f32_16x16x32_bf16(Ahi.v, bf, acc[n8], 0, 0, 0);
                acc[n8] = __builtin_amdgcn_mfma_f32_16x16x32_bf16(Ami.v, bf, acc[n8], 0, 0, 0);
            }
        }

        // prefetch next tile's x (loop-carried; pinned by sched_barrier)
        {
            const int mtn = (mt + 8192 < NMT) ? mt + 8192 : mt;
            const float* xn = x + (size_t)mtn * 16 * 128 + r * 128 + g * 8;
            xp0 = *reinterpret_cast<const f32x4*>(xn);
            xp1 = *reinterpret_cast<const f32x4*>(xn + 4);
            xp2 = *reinterpret_cast<const f32x4*>(xn + 32);
            xp3 = *reinterpret_cast<const f32x4*>(xn + 36);
            xp4 = *reinterpret_cast<const f32x4*>(xn + 64);
            xp5 = *reinterpret_cast<const f32x4*>(xn + 68);
            xp6 = *reinterpret_cast<const f32x4*>(xn + 96);
            xp7 = *reinterpret_cast<const f32x4*>(xn + 100);
        }
        __builtin_amdgcn_sched_barrier(0);

        asum += __shfl_xor(asum, 16);
        asum += __shfl_xor(asum, 32);
        float bndr[4];
#pragma unroll
        for (int reg = 0; reg < 4; ++reg)
            bndr[reg] = __shfl(asum, (lane >> 4) * 4 + reg) * EPS;

        // ballot bit-transpose: sign + flag bytes (r18-proven)
        uint32_t wsrp = 0, wflg = 0;
#pragma unroll
        for (int n8 = 0; n8 < 8; ++n8) {
            const unsigned long long sb0 = __ballot(acc[n8][0] > 0.0f);
            const unsigned long long sb1 = __ballot(acc[n8][1] > 0.0f);
            const unsigned long long sb2 = __ballot(acc[n8][2] > 0.0f);
            const unsigned long long sb3 = __ballot(acc[n8][3] > 0.0f);
            const unsigned long long fb0 = __ballot(fabsf(acc[n8][0]) <= bndr[0]);
            const unsigned long long fb1 = __ballot(fabsf(acc[n8][1]) <= bndr[1]);
            const unsigned long long fb2 = __ballot(fabsf(acc[n8][2]) <= bndr[2]);
            const unsigned long long fb3 = __ballot(fabsf(acc[n8][3]) <= bndr[3]);
            const unsigned long long sbx = s0 ? sb0 : s1 ? sb1 : s2 ? sb2 : sb3;
            const unsigned long long fbx = s0 ? fb0 : s1 ? fb1 : s2 ? fb2 : fb3;
            if ((n8 & 1) == npar) {
                const int mshift = ((n8 - npar) >> 1) * 8;
                wsrp |= (uint32_t)((sbx >> shb) & 0xffull) << mshift;
                wflg |= (uint32_t)((fbx >> shb) & 0xffull) << mshift;
            }
        }

        const size_t eg = (size_t)(Mb + e);
        if (wflg) {   // rare exact fallback: sequential fmaf, i = 0..127
            const float* xr = x + eg * 128;
            for (uint32_t fb = wflg; fb; fb &= fb - 1) {
                const int bit = __builtin_ctz(fb);        // 8*m + j
                const int m   = bit >> 3;
                const int j   = bit & 7;
                const int k   = (c4 + 4 * m) * 8 + j;
                float s = 0.0f;
#pragma unroll 4
                for (int i8 = 0; i8 < 16; ++i8) {
                    const uint4 tb = *reinterpret_cast<const uint4*>(
                        &T[k * 128 + ((i8 ^ (k & 15)) << 3)]);
                    const f32x4 xA = *reinterpret_cast<const f32x4*>(xr + i8 * 8);
                    const f32x4 xB = *reinterpret_cast<const f32x4*>(xr + i8 * 8 + 4);
                    const uint32_t tu[4] = {tb.x, tb.y, tb.z, tb.w};
                    s = __builtin_fmaf(xA[0], __uint_as_float(tu[0] << 16), s);
                    s = __builtin_fmaf(xA[1], __uint_as_float(tu[0] & 0xFFFF0000u), s);
                    s = __builtin_fmaf(xA[2], __uint_as_float(tu[1] << 16), s);
                    s = __builtin_fmaf(xA[3], __uint_as_float(tu[1] & 0xFFFF0000u), s);
                    s = __builtin_fmaf(xB[0], __uint_as_float(tu[2] << 16), s);
                    s = __builtin_fmaf(xB[1], __uint_as_float(tu[2] & 0xFFFF0000u), s);
                    s = __builtin_fmaf(xB[2], __uint_as_float(tu[3] << 16), s);
                    s = __builtin_fmaf(xB[3], __uint_as_float(tu[3] & 0xFFFF0000u), s);
                }
                wsrp = (wsrp & ~(1u << bit)) | ((s > 0.0f) ? (1u << bit) : 0u);
            }
        }

        // ---- phase 2: table lookups + direct stores (no hash, no rec) ----
        float wv[4][8];
#pragma unroll
        for (int m = 0; m < 4; ++m) {
            const int      cc  = c4 + 4 * m;
            const uint32_t srp = (wsrp >> (8 * m)) & 0xFFu;
            const int      ti  = (cc << 8) | (int)srp;
            const uint32_t loc = locTab[ti];

            const float f0 = (float)loc;
            float* oi = out_idx + eg * 128 + cc * 8;
            *reinterpret_cast<f32x4*>(oi)     = (f32x4){f0, f0 + 1.f, f0 + 2.f, f0 + 3.f};
            *reinterpret_cast<f32x4*>(oi + 4) = (f32x4){f0 + 4.f, f0 + 5.f, f0 + 6.f, f0 + 7.f};

            const f32x4 w0 = *reinterpret_cast<const f32x4*>(wTab + (size_t)ti * 8);
            const f32x4 w1 = *reinterpret_cast<const f32x4*>(wTab + (size_t)ti * 8 + 4);
#pragma unroll
            for (int j = 0; j < 4; ++j) { wv[m][j] = w0[j]; wv[m][4 + j] = w1[j]; }
        }

        // rep pairing is lane-local: tasks m and m+2 are chunks cc and cc+8
#pragma unroll
        for (int m = 0; m < 2; ++m) {
            float* ov = out_val + eg * 64 + (c4 + 4 * m) * 8;
            *reinterpret_cast<f32x4*>(ov) =
                (f32x4){(wv[m][0] + wv[2 + m][0]) * 0.5f, (wv[m][1] + wv[2 + m][1]) * 0.5f,
                        (wv[m][2] + wv[2 + m][2]) * 0.5f, (wv[m][3] + wv[2 + m][3]) * 0.5f};
            *reinterpret_cast<f32x4*>(ov + 4) =
                (f32x4){(wv[m][4] + wv[2 + m][4]) * 0.5f, (wv[m][5] + wv[2 + m][5]) * 0.5f,
                        (wv[m][6] + wv[2 + m][6]) * 0.5f, (wv[m][7] + wv[2 + m][7]) * 0.5f};
        }
    }
}

extern "C" void kernel_launch(void* const* d_in, const int* in_sizes, int n_in,
                              void* d_out, int out_size, void* d_ws, size_t ws_size,
                              hipStream_t stream) {
    const float* x   = (const float*)d_in[0];
    const float* hw  = (const float*)d_in[1];
    const float* lsh = (const float*)d_in[2];
    const void*  rnd = (const void*)d_in[3];

    float* out_idx = (float*)d_out;
    float* out_val = out_idx + (size_t)BATCH * 128;

    uint8_t*  ws     = (uint8_t*)d_ws;
    uint32_t* locTab = (uint32_t*)ws;                 // 16 KB
    float*    wTab   = (float*)(ws + 4096 * 4);       // 128 KB

    lma_tab   <<<16, 256, 0, stream>>>(hw, rnd, locTab, wTab);
    lma_fusedT<<<2048, 256, 0, stream>>>(x, lsh, locTab, wTab, out_idx, out_val);
}

// Round 27
// 215.476 us; speedup vs baseline: 1.0177x; 1.0177x over previous
//
#include <hip/hip_runtime.h>
#include <stdint.h>

typedef __attribute__((ext_vector_type(8))) short short8;
typedef __attribute__((ext_vector_type(4))) float f32x4;

constexpr int      BATCH    = 524288;
constexpr int      ARRAY_SZ = 262144;
constexpr uint64_t PRIME    = 2038074743ull;
constexpr uint32_t RANGE    = 262137u;          // ARRAY_SZ - 8 + 1
constexpr int      NMT      = BATCH / 16;       // 32768 M-tiles of 16 elements
// Sign-certainty bound, 2-split (hi+mid) MFMA vs sequential-fmaf reference
// (derivation r17, verified absmax 0.0 r17-r26): total error < 5.4e-5 *
// Sum|x|, margin EPS = 8e-5. Flagged entries recomputed with the sequential
// fmaf chain proven bit-exact in rounds 1-26.
constexpr float    EPS      = 8e-5f;

__device__ __forceinline__ void load_hash_consts(const void* rnd_raw,
                                                 uint64_t& HA, uint64_t& HB, uint64_t& HC0)
{
    const uint64_t first8 = *reinterpret_cast<const uint64_t*>(rnd_raw);
    if (first8 == PRIME) {
        const long long* r64 = reinterpret_cast<const long long*>(rnd_raw);
        HA = (uint64_t)r64[1]; HB = (uint64_t)r64[2]; HC0 = (uint64_t)r64[3];
    } else {
        const int* r32 = reinterpret_cast<const int*>(rnd_raw);
        HA  = (uint64_t)(uint32_t)r32[1];
        HB  = (uint64_t)(uint32_t)r32[2];
        HC0 = (uint64_t)(uint32_t)r32[3];
    }
}

// ===== Kernel 0: precompute loc + w tables for all (chunk, srp) combos =====
__global__ __launch_bounds__(256, 1)
void lma_tab(const float* __restrict__ hw,
             const void* __restrict__ rnd_raw,
             uint32_t* __restrict__ locTab,   // [4096]
             float* __restrict__ wTab)        // [4096][8]
{
    uint64_t HA, HB, HC0;
    load_hash_consts(rnd_raw, HA, HB, HC0);

    const int t   = blockIdx.x * 256 + threadIdx.x;   // 0..4095
    const int srp = t & 255;
    const int cc  = t >> 8;                           // 0..15
    const int cch = cc & 7;

    const uint64_t hh  = (HA * (uint64_t)srp + HB * (uint64_t)cch + HC0) % PRIME;
    const uint32_t loc = (uint32_t)hh % RANGE + ((cc >> 3) ? (uint32_t)ARRAY_SZ : 0u);
    locTab[t] = loc;
#pragma unroll
    for (int j = 0; j < 8; ++j) wTab[t * 8 + j] = hw[loc + j];
}

// ===== Main kernel: MFMA + ballot + table lookups + direct stores =====
// (256,3): empirical optimum of the occupancy-cap sweep —
// (256,2)=219.4us, (256,3)=215.6us, (256,4)=219.3us.
__global__ __launch_bounds__(256, 3)
void lma_fusedT(const float* __restrict__ x,
                const float* __restrict__ lsh,
                const uint32_t* __restrict__ locTab,
                const float* __restrict__ wTab,
                float* __restrict__ out_idx,   // B*128 floats (idx as f32)
                float* __restrict__ out_val)   // B*64 floats
{
    __shared__ unsigned short T[128 * 128];   // lsh^T bf16, XOR-swizzled

    const int tid  = threadIdx.x;
    const int lane = tid & 63;
    const int wid  = __builtin_amdgcn_readfirstlane(tid >> 6);

    for (int it = 0; it < 16; ++it) {
        const int flat4 = it * 256 + tid;
        const int i  = flat4 >> 5;
        const int n4 = (flat4 & 31) << 2;
        const f32x4 v = *reinterpret_cast<const f32x4*>(lsh + i * 128 + n4);
#pragma unroll
        for (int d = 0; d < 4; ++d) {
            const int n = n4 + d;
            T[n * 128 + (((i >> 3) ^ (n & 15)) << 3) + (i & 7)] =
                (unsigned short)(__float_as_uint(v[d]) >> 16);
        }
    }
    __syncthreads();

    const int r    = lane & 15;
    const int g    = lane >> 4;
    const int e    = lane >> 2;
    const int c4   = lane & 3;
    const int hf   = c4 & 1;
    const int npar = c4 >> 1;
    const int shb  = 16 * (e >> 2) + 8 * hf;
    const int sel  = e & 3;
    const bool s0 = (sel == 0), s1 = (sel == 1), s2 = (sel == 2);

    const int mt0 = blockIdx.x * 4 + wid;            // grid 2048 -> stride 8192
    f32x4 xp0, xp1, xp2, xp3, xp4, xp5, xp6, xp7;
    {
        const float* xn = x + (size_t)mt0 * 16 * 128 + r * 128 + g * 8;
        xp0 = *reinterpret_cast<const f32x4*>(xn);
        xp1 = *reinterpret_cast<const f32x4*>(xn + 4);
        xp2 = *reinterpret_cast<const f32x4*>(xn + 32);
        xp3 = *reinterpret_cast<const f32x4*>(xn + 36);
        xp4 = *reinterpret_cast<const f32x4*>(xn + 64);
        xp5 = *reinterpret_cast<const f32x4*>(xn + 68);
        xp6 = *reinterpret_cast<const f32x4*>(xn + 96);
        xp7 = *reinterpret_cast<const f32x4*>(xn + 100);
    }

#pragma unroll 1
    for (int mt = mt0; mt < NMT; mt += 8192) {
        const int Mb = mt * 16;

        f32x4 acc[8];
#pragma unroll
        for (int n8 = 0; n8 < 8; ++n8) acc[n8] = (f32x4)(0.0f);
        float asum = 0.0f;

#pragma unroll
        for (int ks = 0; ks < 4; ++ks) {
            const f32x4 xa = (ks == 0) ? xp0 : (ks == 1) ? xp2 : (ks == 2) ? xp4 : xp6;
            const f32x4 xc = (ks == 0) ? xp1 : (ks == 1) ? xp3 : (ks == 2) ? xp5 : xp7;
            float xs[8] = {xa[0], xa[1], xa[2], xa[3], xc[0], xc[1], xc[2], xc[3]};
#pragma unroll
            for (int j = 0; j < 8; ++j) asum += fabsf(xs[j]);

            union { uint32_t u[4]; short8 v; } Ahi, Ami;
#pragma unroll
            for (int p = 0; p < 4; ++p) {
                const uint32_t b0 = __float_as_uint(xs[2 * p]);
                const uint32_t b1 = __float_as_uint(xs[2 * p + 1]);
                const uint32_t h0 = b0 & 0xFFFF0000u, h1 = b1 & 0xFFFF0000u;
                const float    t0 = xs[2 * p] - __uint_as_float(h0);
                const float    t1 = xs[2 * p + 1] - __uint_as_float(h1);
                const uint32_t m0 = __float_as_uint(t0) & 0xFFFF0000u;
                const uint32_t m1 = __float_as_uint(t1) & 0xFFFF0000u;
                Ahi.u[p] = h1 | (h0 >> 16);
                Ami.u[p] = m1 | (m0 >> 16);
            }
#pragma unroll
            for (int n8 = 0; n8 < 8; ++n8) {
                const short8 bf = *reinterpret_cast<const short8*>(
                    &T[(n8 * 16 + r) * 128 + (((ks * 4 + g) ^ r) << 3)]);
                acc[n8] = __builtin_amdgcn_mfma_f32_16x16x32_bf16(Ahi.v, bf, acc[n8], 0, 0, 0);
                acc[n8] = __builtin_amdgcn_mfma_f32_16x16x32_bf16(Ami.v, bf, acc[n8], 0, 0, 0);
            }
        }

        // prefetch next tile's x (loop-carried; pinned by sched_barrier)
        {
            const int mtn = (mt + 8192 < NMT) ? mt + 8192 : mt;
            const float* xn = x + (size_t)mtn * 16 * 128 + r * 128 + g * 8;
            xp0 = *reinterpret_cast<const f32x4*>(xn);
            xp1 = *reinterpret_cast<const f32x4*>(xn + 4);
            xp2 = *reinterpret_cast<const f32x4*>(xn + 32);
            xp3 = *reinterpret_cast<const f32x4*>(xn + 36);
            xp4 = *reinterpret_cast<const f32x4*>(xn + 64);
            xp5 = *reinterpret_cast<const f32x4*>(xn + 68);
            xp6 = *reinterpret_cast<const f32x4*>(xn + 96);
            xp7 = *reinterpret_cast<const f32x4*>(xn + 100);
        }
        __builtin_amdgcn_sched_barrier(0);

        asum += __shfl_xor(asum, 16);
        asum += __shfl_xor(asum, 32);
        float bndr[4];
#pragma unroll
        for (int reg = 0; reg < 4; ++reg)
            bndr[reg] = __shfl(asum, (lane >> 4) * 4 + reg) * EPS;

        // ballot bit-transpose: sign + flag bytes (r18-proven)
        uint32_t wsrp = 0, wflg = 0;
#pragma unroll
        for (int n8 = 0; n8 < 8; ++n8) {
            const unsigned long long sb0 = __ballot(acc[n8][0] > 0.0f);
            const unsigned long long sb1 = __ballot(acc[n8][1] > 0.0f);
            const unsigned long long sb2 = __ballot(acc[n8][2] > 0.0f);
            const unsigned long long sb3 = __ballot(acc[n8][3] > 0.0f);
            const unsigned long long fb0 = __ballot(fabsf(acc[n8][0]) <= bndr[0]);
            const unsigned long long fb1 = __ballot(fabsf(acc[n8][1]) <= bndr[1]);
            const unsigned long long fb2 = __ballot(fabsf(acc[n8][2]) <= bndr[2]);
            const unsigned long long fb3 = __ballot(fabsf(acc[n8][3]) <= bndr[3]);
            const unsigned long long sbx = s0 ? sb0 : s1 ? sb1 : s2 ? sb2 : sb3;
            const unsigned long long fbx = s0 ? fb0 : s1 ? fb1 : s2 ? fb2 : fb3;
            if ((n8 & 1) == npar) {
                const int mshift = ((n8 - npar) >> 1) * 8;
                wsrp |= (uint32_t)((sbx >> shb) & 0xffull) << mshift;
                wflg |= (uint32_t)((fbx >> shb) & 0xffull) << mshift;
            }
        }

        const size_t eg = (size_t)(Mb + e);
        if (wflg) {   // rare exact fallback: sequential fmaf, i = 0..127
            const float* xr = x + eg * 128;
            for (uint32_t fb = wflg; fb; fb &= fb - 1) {
                const int bit = __builtin_ctz(fb);        // 8*m + j
                const int m   = bit >> 3;
                const int j   = bit & 7;
                const int k   = (c4 + 4 * m) * 8 + j;
                float s = 0.0f;
#pragma unroll 4
                for (int i8 = 0; i8 < 16; ++i8) {
                    const uint4 tb = *reinterpret_cast<const uint4*>(
                        &T[k * 128 + ((i8 ^ (k & 15)) << 3)]);
                    const f32x4 xA = *reinterpret_cast<const f32x4*>(xr + i8 * 8);
                    const f32x4 xB = *reinterpret_cast<const f32x4*>(xr + i8 * 8 + 4);
                    const uint32_t tu[4] = {tb.x, tb.y, tb.z, tb.w};
                    s = __builtin_fmaf(xA[0], __uint_as_float(tu[0] << 16), s);
                    s = __builtin_fmaf(xA[1], __uint_as_float(tu[0] & 0xFFFF0000u), s);
                    s = __builtin_fmaf(xA[2], __uint_as_float(tu[1] << 16), s);
                    s = __builtin_fmaf(xA[3], __uint_as_float(tu[1] & 0xFFFF0000u), s);
                    s = __builtin_fmaf(xB[0], __uint_as_float(tu[2] << 16), s);
                    s = __builtin_fmaf(xB[1], __uint_as_float(tu[2] & 0xFFFF0000u), s);
                    s = __builtin_fmaf(xB[2], __uint_as_float(tu[3] << 16), s);
                    s = __builtin_fmaf(xB[3], __uint_as_float(tu[3] & 0xFFFF0000u), s);
                }
                wsrp = (wsrp & ~(1u << bit)) | ((s > 0.0f) ? (1u << bit) : 0u);
            }
        }

        // ---- phase 2: table lookups + direct stores (no hash, no rec) ----
        float wv[4][8];
#pragma unroll
        for (int m = 0; m < 4; ++m) {
            const int      cc  = c4 + 4 * m;
            const uint32_t srp = (wsrp >> (8 * m)) & 0xFFu;
            const int      ti  = (cc << 8) | (int)srp;
            const uint32_t loc = locTab[ti];

            const float f0 = (float)loc;
            float* oi = out_idx + eg * 128 + cc * 8;
            *reinterpret_cast<f32x4*>(oi)     = (f32x4){f0, f0 + 1.f, f0 + 2.f, f0 + 3.f};
            *reinterpret_cast<f32x4*>(oi + 4) = (f32x4){f0 + 4.f, f0 + 5.f, f0 + 6.f, f0 + 7.f};

            const f32x4 w0 = *reinterpret_cast<const f32x4*>(wTab + (size_t)ti * 8);
            const f32x4 w1 = *reinterpret_cast<const f32x4*>(wTab + (size_t)ti * 8 + 4);
#pragma unroll
            for (int j = 0; j < 4; ++j) { wv[m][j] = w0[j]; wv[m][4 + j] = w1[j]; }
        }

        // rep pairing is lane-local: tasks m and m+2 are chunks cc and cc+8
#pragma unroll
        for (int m = 0; m < 2; ++m) {
            float* ov = out_val + eg * 64 + (c4 + 4 * m) * 8;
            *reinterpret_cast<f32x4*>(ov) =
                (f32x4){(wv[m][0] + wv[2 + m][0]) * 0.5f, (wv[m][1] + wv[2 + m][1]) * 0.5f,
                        (wv[m][2] + wv[2 + m][2]) * 0.5f, (wv[m][3] + wv[2 + m][3]) * 0.5f};
            *reinterpret_cast<f32x4*>(ov + 4) =
                (f32x4){(wv[m][4] + wv[2 + m][4]) * 0.5f, (wv[m][5] + wv[2 + m][5]) * 0.5f,
                        (wv[m][6] + wv[2 + m][6]) * 0.5f, (wv[m][7] + wv[2 + m][7]) * 0.5f};
        }
    }
}

extern "C" void kernel_launch(void* const* d_in, const int* in_sizes, int n_in,
                              void* d_out, int out_size, void* d_ws, size_t ws_size,
                              hipStream_t stream) {
    const float* x   = (const float*)d_in[0];
    const float* hw  = (const float*)d_in[1];
    const float* lsh = (const float*)d_in[2];
    const void*  rnd = (const void*)d_in[3];

    float* out_idx = (float*)d_out;
    float* out_val = out_idx + (size_t)BATCH * 128;

    uint8_t*  ws     = (uint8_t*)d_ws;
    uint32_t* locTab = (uint32_t*)ws;                 // 16 KB
    float*    wTab   = (float*)(ws + 4096 * 4);       // 128 KB

    lma_tab   <<<16, 256, 0, stream>>>(hw, rnd, locTab, wTab);
    lma_fusedT<<<2048, 256, 0, stream>>>(x, lsh, locTab, wTab, out_idx, out_val);
}